// Round 9
// baseline (137.085 us; speedup 1.0000x reference)
//
#include <hip/hip_runtime.h>
#include <hip/hip_fp16.h>

// x (8,320,320) f32, u (8,12,320,320,2) f32 -> out (8,12,320,320) f32.
#define PP 8
#define FF 12
#define MM 320
#define NN 320
#define TILE 32
#define HALO 16
#define LW   (TILE + 2 * HALO)   // 64 staged rows/cols
#define PW   33                  // 32-bit words per LDS row (32 data + 1 pad)
#define FPB  6                   // frames per block (12 = 2 groups of 6)

typedef float fvec4 __attribute__((ext_vector_type(4)));

// Tile stored as fp16 pairs in TWO copies:
//   hA[r][c] = ( px[2c],   px[2c+1] )   c in [0,32)
//   hB[r][c] = ( px[2c+1], px[2c+2] )
// so the horizontal corner pair at any column lx is ONE aligned 32-bit word;
// row below at +PW words -> one ds_read2_b32 per pixel.
__global__ __launch_bounds__(256, 8) void warp_tile_kernel(
    const float* __restrict__ x,
    const float* __restrict__ u,
    float* __restrict__ out)
{
    __shared__ unsigned int hA[LW * PW];   // 8,448 B
    __shared__ unsigned int hB[LW * PW];   // total 16,896 B -> 8 blocks/CU

    int zz = blockIdx.z;                   // p * 2 + fgroup
    int p  = zz >> 1;
    int f0 = (zz & 1) * FPB;
    int i0 = blockIdx.y * TILE;
    int j0 = blockIdx.x * TILE;

    const float* __restrict__ img = x + p * (MM * NN);

    // Phase 1: stage copy A (zero outside image; col 4-groups are 4-aligned
    // vs the image so each is fully in or out). 4 iters/thread.
    for (int idx = threadIdx.x; idx < LW * (LW / 4); idx += 256) {
        int r  = idx >> 4;                 // /16
        int c4 = idx & 15;
        int gr = i0 - HALO + r;
        int gc = j0 - HALO + c4 * 4;
        fvec4 v = {0.0f, 0.0f, 0.0f, 0.0f};
        if ((unsigned)gr < MM && (unsigned)gc < NN)
            v = *(const fvec4*)(img + gr * NN + gc);
        __half2 w0 = __floats2half2_rn(v.x, v.y);
        __half2 w1 = __floats2half2_rn(v.z, v.w);
        unsigned int* dst = &hA[r * PW + c4 * 2];
        dst[0] = *(unsigned int*)&w0;
        dst[1] = *(unsigned int*)&w1;
    }
    __syncthreads();

    // Phase 2: copy B = funnel shift of adjacent A words (c=31 reads the pad
    // word — in-bounds, value never consumed). 8 iters/thread.
    for (int idx = threadIdx.x; idx < LW * (LW / 2); idx += 256) {
        int r = idx >> 5;                  // /32
        int c = idx & 31;
        unsigned int a0 = hA[r * PW + c];
        unsigned int a1 = hA[r * PW + c + 1];
        hB[r * PW + c] = __builtin_amdgcn_alignbit(a1, a0, 16);
    }
    __syncthreads();

    // Thread layout: 4 consecutive cols x 1 row per thread (256 thr = 32x32).
    int tcol = ((int)threadIdx.x & 7) * 4;    // 0..28
    int row0 = ((int)threadIdx.x >> 3);       // 0..31
    int gi = i0 + row0;
    int gj = j0 + tcol;

    for (int ff = 0; ff < FPB; ++ff) {
        int pf = p * FF + (f0 + ff);
        const float* __restrict__ ubase = u + (size_t)pf * (MM * NN * 2);
        float* __restrict__ obase = out + (size_t)pf * (MM * NN);

        const fvec4* up = (const fvec4*)(ubase + 2 * ((size_t)gi * NN + gj));
        fvec4 ua = up[0];
        fvec4 ub = up[1];
        float dx[4] = {ua.x, ua.z, ub.x, ub.z};
        float dy[4] = {ua.y, ua.w, ub.y, ub.w};

        float res[4];
#pragma unroll
        for (int k = 0; k < 4; ++k) {
            float sx = (float)(gj + k) + dx[k];
            float sy = (float)gi + dy[k];
            float fx0 = floorf(sx);
            float fy0 = floorf(sy);
            float wx = sx - fx0;
            float wy = sy - fy0;
            int x0i = (int)fx0;
            int y0i = (int)fy0;

            int lx = x0i - (j0 - HALO);
            int ly = y0i - (i0 - HALO);

            float v00, v01, v10, v11;
            if ((unsigned)lx < (LW - 1) && (unsigned)ly < (LW - 1)) {
                const unsigned int* base = (lx & 1) ? hB : hA;
                int w = ly * PW + (lx >> 1);
                unsigned int t0 = base[w];        // (v00, v01)
                unsigned int t1 = base[w + PW];   // (v10, v11)
                float2 r0 = __half22float2(*(const __half2*)&t0);
                float2 r1 = __half22float2(*(const __half2*)&t1);
                v00 = r0.x; v01 = r0.y;
                v10 = r1.x; v11 = r1.y;
            } else {
                // Rare (|flow| beyond halo): predicated global gather (fp32).
                int xc0 = min(max(x0i,     0), NN - 1);
                int xc1 = min(max(x0i + 1, 0), NN - 1);
                int yc0 = min(max(y0i,     0), MM - 1);
                int yc1 = min(max(y0i + 1, 0), MM - 1);
                bool vx0 = (x0i >= 0)     & (x0i < NN);
                bool vx1 = (x0i + 1 >= 0) & (x0i + 1 < NN);
                bool vy0 = (y0i >= 0)     & (y0i < MM);
                bool vy1 = (y0i + 1 >= 0) & (y0i + 1 < MM);
                int r0i = yc0 * NN;
                int r1i = yc1 * NN;
                v00 = (vy0 & vx0) ? img[r0i + xc0] : 0.0f;
                v01 = (vy0 & vx1) ? img[r0i + xc1] : 0.0f;
                v10 = (vy1 & vx0) ? img[r1i + xc0] : 0.0f;
                v11 = (vy1 & vx1) ? img[r1i + xc1] : 0.0f;
            }

            float vt = fmaf(wx, v01 - v00, v00);
            float vb = fmaf(wx, v11 - v10, v10);
            res[k] = fmaf(wy, vb - vt, vt);
        }

        fvec4 o = {res[0], res[1], res[2], res[3]};
        __builtin_nontemporal_store(o, (fvec4*)(obase + (size_t)gi * NN + gj));
    }
}

extern "C" void kernel_launch(void* const* d_in, const int* in_sizes, int n_in,
                              void* d_out, int out_size, void* d_ws, size_t ws_size,
                              hipStream_t stream) {
    const float* x = (const float*)d_in[0];
    const float* u = (const float*)d_in[1];
    float* out = (float*)d_out;

    dim3 grid(NN / TILE, MM / TILE, PP * (FF / FPB));  // 10 x 10 x 16 = 1600
    dim3 block(256);
    warp_tile_kernel<<<grid, block, 0, stream>>>(x, u, out);
}